// Round 3
// baseline (237.975 us; speedup 1.0000x reference)
//
#include <hip/hip_runtime.h>
#include <cstddef>

#define D_  32
#define N_  1024
#define T_  256
#define NT_ 1280
#define B_  32
#define RB  32            // rows per block; divides 1024 and 256 -> bands never cross s/t row boundary
#define NBANDS (NT_/RB)   // 40

typedef float vf4 __attribute__((ext_vector_type(4)));   // clang vector: valid for nontemporal builtins

__device__ __forceinline__ float fast_tanh(float x) {
    // tanh(x) = 1 - 2/(e^{2x}+1); saturates to +-1, no NaN paths. err ~1e-6.
    float e = __expf(2.0f * x);
    return 1.0f - 2.0f * __builtin_amdgcn_rcpf(e + 1.0f);
}

__device__ __forceinline__ float dot32(const float* __restrict__ x,
                                       const float* __restrict__ w) {
    const float4* xv = (const float4*)x;
    const float4* wv = (const float4*)w;
    float a = 0.f;
    #pragma unroll
    for (int k = 0; k < D_ / 4; ++k) {
        float4 xx = xv[k], ww = wv[k];
        a = fmaf(xx.x, ww.x, a);
        a = fmaf(xx.y, ww.y, a);
        a = fmaf(xx.z, ww.z, a);
        a = fmaf(xx.w, ww.w, a);
    }
    return a;
}

// Each block: one batch b, RB=32 full-width rows. Output region per block is
// 32*5120B = 160KB fully contiguous; each wave writes 8 consecutive rows
// (40KB sequential) -> matches the ~6.5 TB/s fill-kernel store pattern.
__global__ __launch_bounds__(256) void mlp_adj_kernel(
    const float* __restrict__ S,  const float* __restrict__ Tn,
    const float* __restrict__ Wr, const float* __restrict__ br,
    const float* __restrict__ Wm, const float* __restrict__ bm,
    float* __restrict__ out)
{
    __shared__ float colA[NT_], colM[NT_];
    __shared__ float rowP[4][RB];   // [0]=A seg0, [1]=M seg0, [2]=A seg1, [3]=M seg1

    const int band = blockIdx.x % NBANDS;
    const int b    = blockIdx.x / NBANDS;
    const int i0   = band * RB;
    const int rr   = (i0 >= N_);          // row region: 0=spatial 1=temporal
    const int r1   = rr ? 3 : 0;          // relation for col segment 0 (spatial cols): ss / ts
    const int r2   = rr ? 1 : 2;          // relation for col segment 1 (temporal cols): st / tt
    const int tid  = threadIdx.x;

    const float* Xrow = rr ? (Tn + ((size_t)b * T_ + (i0 - N_)) * D_)
                           : (S  + ((size_t)b * N_ +  i0      ) * D_);

    // ---- row projections: 32 rows x {A,M} x {seg0,seg1} = 128 dots, threads 0..127 ----
    if (tid < 4 * RB) {
        const int i     = tid & (RB - 1);
        const int which = tid >> 5;                        // 0:A1 1:M1 2:A2 3:M2
        const int rsel  = (which & 2) ? r2 : r1;
        const float* w  = ((which & 1) ? Wm : Wr) + rsel * 2 * D_;   // row half [:D]
        rowP[which][i] = dot32(Xrow + (size_t)i * D_, w);
    }

    // ---- col projections for ALL 1280 cols; biases folded here (bias depends on col segment) ----
    {
        const float* wrC1 = Wr + r1 * 2 * D_ + D_;   // col half [D:]
        const float* wmC1 = Wm + r1 * 2 * D_ + D_;
        const float* wrC2 = Wr + r2 * 2 * D_ + D_;
        const float* wmC2 = Wm + r2 * 2 * D_ + D_;
        const float  bA1 = br[r1], bM1 = bm[r1], bA2 = br[r2], bM2 = bm[r2];
        #pragma unroll
        for (int c = 0; c < 4; ++c) {                 // spatial cols 0..1023
            const int j = c * 256 + tid;
            const float* xj = S + ((size_t)b * N_ + j) * D_;
            colA[j] = dot32(xj, wrC1) + bA1;
            colM[j] = dot32(xj, wmC1) + bM1;
        }
        {                                              // temporal cols 1024..1279
            const float* xj = Tn + ((size_t)b * T_ + tid) * D_;
            colA[1024 + tid] = dot32(xj, wrC2) + bA2;
            colM[1024 + tid] = dot32(xj, wmC2) + bM2;
        }
    }
    __syncthreads();

    // ---- epilogue: lane l owns cols {c*256 + l*4 .. +3, c=0..4}; col values cached in regs ----
    const int l = tid & 63;
    const int w = tid >> 6;
    float4 cAv[5], cMv[5];
    #pragma unroll
    for (int c = 0; c < 5; ++c) {
        cAv[c] = *(const float4*)&colA[c * 256 + l * 4];
        cMv[c] = *(const float4*)&colM[c * 256 + l * 4];
    }
    const int rbase = w * 8;                 // 8 consecutive rows per wave
    float rA1[8], rM1[8], rA2[8], rM2[8];
    #pragma unroll
    for (int k = 0; k < 8; ++k) {
        rA1[k] = rowP[0][rbase + k];
        rM1[k] = rowP[1][rbase + k];
        rA2[k] = rowP[2][rbase + k];
        rM2[k] = rowP[3][rbase + k];
    }

    float* outp = out + ((size_t)(b * NT_ + i0 + rbase)) * NT_ + l * 4;
    #pragma unroll 2
    for (int k = 0; k < 8; ++k) {
        float* rp = outp + (size_t)k * NT_;
        #pragma unroll
        for (int c = 0; c < 5; ++c) {
            const float ra = (c < 4) ? rA1[k] : rA2[k];   // chunk 4 = temporal col segment
            const float rm = (c < 4) ? rM1[k] : rM2[k];
            vf4 o;
            o.x = fast_tanh((ra + cAv[c].x) * fmaxf(rm + cMv[c].x, 0.f));
            o.y = fast_tanh((ra + cAv[c].y) * fmaxf(rm + cMv[c].y, 0.f));
            o.z = fast_tanh((ra + cAv[c].z) * fmaxf(rm + cMv[c].z, 0.f));
            o.w = fast_tanh((ra + cAv[c].w) * fmaxf(rm + cMv[c].w, 0.f));
            __builtin_nontemporal_store(o, (vf4*)(rp + c * 256));  // 64 lanes x 16B = 1KB, rows contiguous
        }
    }
}

extern "C" void kernel_launch(void* const* d_in, const int* in_sizes, int n_in,
                              void* d_out, int out_size, void* d_ws, size_t ws_size,
                              hipStream_t stream) {
    const float* S  = (const float*)d_in[0];  // spatial_nodes  [32,1024,32]
    const float* Tn = (const float*)d_in[1];  // temporal_nodes [32,256,32]
    const float* Wr = (const float*)d_in[2];  // W_rel  [4,64]
    const float* br = (const float*)d_in[3];  // b_rel  [4]
    const float* Wm = (const float*)d_in[4];  // W_mask [4,64]
    const float* bm = (const float*)d_in[5];  // b_mask [4]
    float* out = (float*)d_out;               // [32,1280,1280] fp32

    const int grid = B_ * NBANDS;             // 1280 blocks, 5 per CU
    mlp_adj_kernel<<<grid, 256, 0, stream>>>(S, Tn, Wr, br, Wm, bm, out);
}

// Round 4
// 214.872 us; speedup vs baseline: 1.1075x; 1.1075x over previous
//
#include <hip/hip_runtime.h>
#include <cstddef>

#define D_  32
#define N_  1024
#define T_  256
#define NT_ 1280
#define B_  32

// d_ws float layout (total 327,680 floats = 1.31 MB):
//   RA [B][NT][2]  offset 0       row adj proj, slot=seg_j, bias folded
//   RM [B][NT][2]  offset 81920   row mask proj, slot=seg_j, bias folded
//   CA [2][B][NT]  offset 163840  col adj proj, plane=seg_i
//   CM [2][B][NT]  offset 245760  col mask proj, plane=seg_i
#define RA_OFF 0
#define RM_OFF (B_*NT_*2)
#define CA_OFF (2*B_*NT_*2)
#define CM_OFF (CA_OFF + 2*B_*NT_)

__device__ __forceinline__ float fast_tanh(float x) {
    // tanh(x) = 1 - 2/(e^{2x}+1); saturates to +-1, no NaN paths. err ~1e-6.
    float e = __expf(2.0f * x);
    return 1.0f - 2.0f * __builtin_amdgcn_rcpf(e + 1.0f);
}

__device__ __forceinline__ float dot8(const float4* __restrict__ xv,
                                      const float* __restrict__ w) {
    const float4* wv = (const float4*)w;
    float a = 0.f;
    #pragma unroll
    for (int k = 0; k < D_ / 4; ++k) {
        float4 ww = wv[k];
        a = fmaf(xv[k].x, ww.x, a);
        a = fmaf(xv[k].y, ww.y, a);
        a = fmaf(xv[k].z, ww.z, a);
        a = fmaf(xv[k].w, ww.w, a);
    }
    return a;
}

// One thread per node (b, idx): computes all 8 projections.
// rel(si,sj): ss=0 (0,0), tt=1 (1,1), st=2 (0,1), ts=3 (1,0).
__global__ __launch_bounds__(256) void proj_kernel(
    const float* __restrict__ S,  const float* __restrict__ Tn,
    const float* __restrict__ Wr, const float* __restrict__ br,
    const float* __restrict__ Wm, const float* __restrict__ bm,
    float* __restrict__ ws)
{
    const int idx = blockIdx.x * 256 + threadIdx.x;   // node 0..1279
    const int b   = blockIdx.y;
    const int seg = (idx >= N_);                      // this node's region
    const float* x = seg ? (Tn + ((size_t)b * T_ + (idx - N_)) * D_)
                         : (S  + ((size_t)b * N_ +  idx      ) * D_);
    float4 xv[D_ / 4];
    #pragma unroll
    for (int k = 0; k < D_ / 4; ++k) xv[k] = ((const float4*)x)[k];

    // --- as a ROW i (si=seg): slot sj=0 -> rel(seg,0); sj=1 -> rel(seg,1) ---
    const int rr0 = seg ? 3 : 0;     // rel(seg,0): ts / ss
    const int rr1 = seg ? 1 : 2;     // rel(seg,1): tt / st
    float* RA = ws + RA_OFF;  float* RM = ws + RM_OFF;
    const size_t ri = ((size_t)b * NT_ + idx) * 2;
    RA[ri + 0] = dot8(xv, Wr + rr0 * 2 * D_) + br[rr0];   // row half [:D]
    RA[ri + 1] = dot8(xv, Wr + rr1 * 2 * D_) + br[rr1];
    RM[ri + 0] = dot8(xv, Wm + rr0 * 2 * D_) + bm[rr0];
    RM[ri + 1] = dot8(xv, Wm + rr1 * 2 * D_) + bm[rr1];

    // --- as a COL j (sj=seg): plane si=0 -> rel(0,seg); si=1 -> rel(1,seg) ---
    const int rc0 = seg ? 2 : 0;     // rel(0,seg): st / ss
    const int rc1 = seg ? 1 : 3;     // rel(1,seg): tt / ts
    float* CA = ws + CA_OFF;  float* CM = ws + CM_OFF;
    const size_t ci = (size_t)b * NT_ + idx;
    CA[0 * B_ * NT_ + ci] = dot8(xv, Wr + rc0 * 2 * D_ + D_);   // col half [D:]
    CA[1 * B_ * NT_ + ci] = dot8(xv, Wr + rc1 * 2 * D_ + D_);
    CM[0 * B_ * NT_ + ci] = dot8(xv, Wm + rc0 * 2 * D_ + D_);
    CM[1 * B_ * NT_ + ci] = dot8(xv, Wm + rc1 * 2 * D_ + D_);
}

// Pure streaming epilogue: block (320 thr, 5 waves) = one contiguous 5KB output
// row; thread = one float4; consecutive blocks = consecutive rows. No LDS, no
// syncthreads, ~30 VGPRs. Waves 0-3: spatial cols (seg_j=0); wave 4: temporal
// (seg_j=1) -> all selects wave-uniform.
__global__ __launch_bounds__(320) void epi_kernel(
    const float* __restrict__ ws, float* __restrict__ out)
{
    const int tid   = threadIdx.x;         // 0..319
    const int i     = blockIdx.x;          // row 0..1279
    const int b     = blockIdx.y;          // batch
    const int seg_i = (i   >= N_);
    const int seg_j = (tid >= 256) ? 1 : 0;

    const float* RA = ws + RA_OFF;
    const float* RM = ws + RM_OFF;
    const float* CA = ws + CA_OFF;
    const float* CM = ws + CM_OFF;

    const float2 rav = *(const float2*)&RA[((size_t)b * NT_ + i) * 2];
    const float2 rmv = *(const float2*)&RM[((size_t)b * NT_ + i) * 2];
    const float  ra  = seg_j ? rav.y : rav.x;
    const float  rm  = seg_j ? rmv.y : rmv.x;

    const int j = tid * 4;
    const size_t cbase = ((size_t)seg_i * B_ + b) * NT_ + j;
    const float4 ca = *(const float4*)&CA[cbase];
    const float4 cm = *(const float4*)&CM[cbase];

    float4 o;
    o.x = fast_tanh((ra + ca.x) * fmaxf(rm + cm.x, 0.f));
    o.y = fast_tanh((ra + ca.y) * fmaxf(rm + cm.y, 0.f));
    o.z = fast_tanh((ra + ca.z) * fmaxf(rm + cm.z, 0.f));
    o.w = fast_tanh((ra + ca.w) * fmaxf(rm + cm.w, 0.f));
    *(float4*)(out + ((size_t)(b * NT_ + i)) * NT_ + j) = o;
}

extern "C" void kernel_launch(void* const* d_in, const int* in_sizes, int n_in,
                              void* d_out, int out_size, void* d_ws, size_t ws_size,
                              hipStream_t stream) {
    const float* S  = (const float*)d_in[0];  // spatial_nodes  [32,1024,32]
    const float* Tn = (const float*)d_in[1];  // temporal_nodes [32,256,32]
    const float* Wr = (const float*)d_in[2];  // W_rel  [4,64]
    const float* br = (const float*)d_in[3];  // b_rel  [4]
    const float* Wm = (const float*)d_in[4];  // W_mask [4,64]
    const float* bm = (const float*)d_in[5];  // b_mask [4]
    float* out = (float*)d_out;               // [32,1280,1280] fp32
    float* ws  = (float*)d_ws;                // needs 1.31 MB

    proj_kernel<<<dim3(NT_ / 256, B_), 256, 0, stream>>>(S, Tn, Wr, br, Wm, bm, ws);
    epi_kernel <<<dim3(NT_, B_),       320, 0, stream>>>(ws, out);
}